// Round 6
// baseline (171.555 us; speedup 1.0000x reference)
//
#include <hip/hip_runtime.h>

// N=64 nodes, H=64, M=32, B=16384.
// Wave-specialized pipeline, single kernel. Grid: 1024 blocks = 64 i x 16 bg;
// each block processes 1024 batch rows as 64 chunks of 16 rows, pipelined 3 deep:
//   wave0: x -> Ha (W1a masked)     [8 MFMA/step]
//   wave1: x -> Hb (W2a masked)     [8 MFMA/step]
//   wave2: Ha,Hb -> R12 (W1b,W2b)   [8 MFMA/step]
//   wave3: R12 -> out (W3a + rank-1 + biases + final dot) [8 MFMA/step]
// Each wave holds ONLY its phase's weights: 8 bf16x8 frags = 32 VGPRs (same named
// W[8] for all waves -> static pressure ~125 regs -> 4 waves/SIMD, no AGPR spill;
// R5 lesson: monolithic 128-reg weight set forced AGPR residency + ~400 VALU/chunk
// copy tax and capped occupancy at 2 waves/SIMD).
// Activations pass through a 12 KB double-buffered per-lane LDS mailbox; K-columns
// of W1b/W2b/W3a are permuted (sigma) so MFMA D regs, after relu+pack, are directly
// the next phase's B-operand fragments (verified R3-R5).

typedef short bf16x8 __attribute__((ext_vector_type(8)));
typedef float f32x4  __attribute__((ext_vector_type(4)));
typedef unsigned int u32x4 __attribute__((ext_vector_type(4)));

#define CHUNKS 64            // 16-row chunks per block (1024 rows)

__device__ __forceinline__ unsigned int pack2(float a, float b) {
    // f32->bf16 pair pack (a -> low16): 2 adds + 1 v_perm
    union { float f; unsigned int u; } ua, ub; ua.f = a; ub.f = b;
    return __builtin_amdgcn_perm(ub.u + 0x8000u, ua.u + 0x8000u, 0x07060302u);
}

__device__ __forceinline__ float bf_lo(unsigned int u) {
    union { unsigned int u; float f; } v; v.u = u << 16; return v.f;
}
__device__ __forceinline__ float bf_hi(unsigned int u) {
    union { unsigned int u; float f; } v; v.u = u & 0xFFFF0000u; return v.f;
}

__device__ __forceinline__ f32x4 mfma16(bf16x8 a, bf16x8 b, f32x4 c) {
    return __builtin_amdgcn_mfma_f32_16x16x32_bf16(a, b, c, 0, 0, 0);
}

// pack two relu'd f32x4 D-blocks into one bf16x8 B-operand fragment
__device__ __forceinline__ bf16x8 pack_frag(f32x4 lo, f32x4 hi) {
    union { u32x4 u; bf16x8 v; } r;
    r.u[0] = pack2(fmaxf(lo[0], 0.f), fmaxf(lo[1], 0.f));
    r.u[1] = pack2(fmaxf(lo[2], 0.f), fmaxf(lo[3], 0.f));
    r.u[2] = pack2(fmaxf(hi[0], 0.f), fmaxf(hi[1], 0.f));
    r.u[3] = pack2(fmaxf(hi[2], 0.f), fmaxf(hi[3], 0.f));
    return r.v;
}

// pack two f32x4 values (no relu) into a bf16x8 fragment
__device__ __forceinline__ bf16x8 pack_vals(f32x4 lo, f32x4 hi) {
    union { u32x4 u; bf16x8 v; } r;
    r.u[0] = pack2(lo[0], lo[1]);
    r.u[1] = pack2(lo[2], lo[3]);
    r.u[2] = pack2(hi[0], hi[1]);
    r.u[3] = pack2(hi[2], hi[3]);
    return r.v;
}

__device__ __forceinline__ bf16x8 cvt_frag2(const float* __restrict__ plo,
                                            const float* __restrict__ phi) {
    return pack_vals(*(const f32x4*)plo, *(const f32x4*)phi);
}

__device__ __forceinline__ bf16x8 cvt_frag2_m(const float* __restrict__ plo,
                                              const float* __restrict__ phi,
                                              const unsigned int* M) {
    f32x4 f0 = *(const f32x4*)plo;
    f32x4 f1 = *(const f32x4*)phi;
    union { u32x4 u; bf16x8 v; } r;
    r.u[0] = pack2(f0[0], f0[1]) & M[0];
    r.u[1] = pack2(f0[2], f0[3]) & M[1];
    r.u[2] = pack2(f1[0], f1[1]) & M[2];
    r.u[3] = pack2(f1[2], f1[3]) & M[3];
    return r.v;
}

__global__ __launch_bounds__(256, 2) void main_kernel(
    const float* __restrict__ x,
    const float* __restrict__ W1a, const float* __restrict__ W1b,
    const float* __restrict__ W2a, const float* __restrict__ W2b,
    const float* __restrict__ W3a, const float* __restrict__ b3a,
    const float* __restrict__ W3b, const float* __restrict__ b3b,
    float* __restrict__ out)
{
    // per-lane mailbox, shorts: Ha[2] @0, Hb[2] @2048, R12[2] @4096 (1024 shorts each)
    __shared__ unsigned short lds[6144];

    const int i    = blockIdx.x & 63;   // same-i blocks -> same XCD (stride 64 % 8 == 0)
    const int bg   = blockIdx.x >> 6;   // 0..15
    const int w    = threadIdx.x >> 6;
    const int lane = threadIdx.x & 63;
    const int q    = lane >> 4;
    const int c0   = lane & 15;
    const int rowbase = bg << 10;       // 1024 rows per block

    // masks zeroing weight input-column i of W1a/W2a (== masking x column i)
    unsigned int M[2][4];
    {
        const unsigned int halfmask = (i & 1) ? 0x0000FFFFu : 0xFFFF0000u;
        const int dz = (i >> 1) & 3;
        #pragma unroll
        for (int s = 0; s < 2; ++s) {
            bool hit = ((i >> 3) == s * 4 + q);
            #pragma unroll
            for (int d = 0; d < 4; ++d)
                M[s][d] = (hit && d == dz) ? halfmask : 0xFFFFFFFFu;
        }
    }

    // ---- per-wave weights: exactly 8 fragments = 32 VGPRs, same names all waves ----
    bf16x8 W[8];
    if (w < 2) {
        // layer 1, branch w: frag elem j = W[i][t*16+c0][s*32+q*8+j], col i zeroed
        const float* p = (w == 0 ? W1a : W2a) + (i << 12);
        #pragma unroll
        for (int t = 0; t < 4; ++t)
            #pragma unroll
            for (int s = 0; s < 2; ++s) {
                int off = (((t << 4) + c0) << 6) + (s << 5) + (q << 3);
                W[t * 2 + s] = cvt_frag2_m(p + off, p + off + 4, M[s]);
            }
    } else if (w == 2) {
        // layer 2 both branches, K permuted: sigma(s,q,j) = 32s + 16(j>>2) + 4q + (j&3)
        const float* p1 = W1b + (i << 11);
        const float* p2 = W2b + (i << 11);
        #pragma unroll
        for (int t = 0; t < 2; ++t)
            #pragma unroll
            for (int s = 0; s < 2; ++s) {
                int base = (((t << 4) + c0) << 6) + (s << 5) + (q << 2);
                W[t * 2 + s]     = cvt_frag2(p1 + base, p1 + base + 16);
                W[4 + t * 2 + s] = cvt_frag2(p2 + base, p2 + base + 16);
            }
    } else {
        // layer 3 (first 64 concat cols), K permuted by sigma
        const float* p3 = W3a + (i << 13);
        #pragma unroll
        for (int t = 0; t < 4; ++t)
            #pragma unroll
            for (int s = 0; s < 2; ++s) {
                int base = (((t << 4) + c0) << 7) + (s << 5) + (q << 2);
                W[t * 2 + s] = cvt_frag2(p3 + base, p3 + base + 16);
            }
    }

    // ---- wave-3 constants (f32 bias + f32 w3b; w3x packed bf16 to save regs) ----
    f32x4 b3av[4], w3bv[4];
    uint2 wxp[4];
    float bb = 0.f, xd_n = 0.f;
    if (w == 3) {
        #pragma unroll
        for (int t = 0; t < 4; ++t) {
            int h0 = (i << 6) + (t << 4) + (q << 2);
            b3av[t] = *(const f32x4*)&b3a[h0];
            w3bv[t] = *(const f32x4*)&W3b[h0];
            float v0 = W3a[(i << 13) + (((t << 4) + (q << 2) + 0) << 7) + 64 + i];
            float v1 = W3a[(i << 13) + (((t << 4) + (q << 2) + 1) << 7) + 64 + i];
            float v2 = W3a[(i << 13) + (((t << 4) + (q << 2) + 2) << 7) + 64 + i];
            float v3 = W3a[(i << 13) + (((t << 4) + (q << 2) + 3) << 7) + 64 + i];
            wxp[t].x = pack2(v0, v1);
            wxp[t].y = pack2(v2, v3);
        }
        bb = b3b[i];
        xd_n = x[((rowbase + c0) << 6) + i];   // chunk 0's xd
    }

    // ---- wave-0/1 x staging (chunk 0 raw f32, prefetched) ----
    f32x4 xr0, xr1, xr2, xr3;
    if (w < 2) {
        const float* xp = x + ((rowbase + c0) << 6) + (q << 3);
        xr0 = *(const f32x4*)xp;       xr1 = *(const f32x4*)(xp + 4);
        xr2 = *(const f32x4*)(xp + 32); xr3 = *(const f32x4*)(xp + 36);
    }

    for (int k = 0; k < CHUNKS + 2; ++k) {
        if (w < 2) {
            if (k < CHUNKS) {
                bf16x8 XB0 = pack_vals(xr0, xr1);
                bf16x8 XB1 = pack_vals(xr2, xr3);
                if (k + 1 < CHUNKS) {   // prefetch next chunk's x
                    const float* xp = x + ((rowbase + ((k + 1) << 4) + c0) << 6) + (q << 3);
                    xr0 = *(const f32x4*)xp;        xr1 = *(const f32x4*)(xp + 4);
                    xr2 = *(const f32x4*)(xp + 32); xr3 = *(const f32x4*)(xp + 36);
                }
                f32x4 a[4];
                #pragma unroll
                for (int t = 0; t < 4; ++t) {
                    f32x4 z = {0.f, 0.f, 0.f, 0.f};
                    f32x4 u = mfma16(W[2 * t], XB0, z);
                    a[t] = mfma16(W[2 * t + 1], XB1, u);
                }
                bf16x8 H0 = pack_frag(a[0], a[1]);
                bf16x8 H1 = pack_frag(a[2], a[3]);
                unsigned short* dst = &lds[(w << 11) + ((k & 1) << 10) + (lane << 3)];
                *(bf16x8*)dst         = H0;
                *(bf16x8*)(dst + 512) = H1;
            }
        } else if (w == 2) {
            int k2 = k - 1;
            if (k2 >= 0 && k2 < CHUNKS) {
                const unsigned short* s1 = &lds[((k2 & 1) << 10) + (lane << 3)];
                const unsigned short* s2 = s1 + 2048;
                bf16x8 HB0 = *(const bf16x8*)s1, HB1 = *(const bf16x8*)(s1 + 512);
                bf16x8 GB0 = *(const bf16x8*)s2, GB1 = *(const bf16x8*)(s2 + 512);
                f32x4 b1[2], b2[2];
                #pragma unroll
                for (int t = 0; t < 2; ++t) {
                    f32x4 z = {0.f, 0.f, 0.f, 0.f};
                    f32x4 u = mfma16(W[2 * t], HB0, z);
                    b1[t] = mfma16(W[2 * t + 1], HB1, u);
                    f32x4 v = mfma16(W[4 + 2 * t], GB0, z);
                    b2[t] = mfma16(W[5 + 2 * t], GB1, v);
                }
                bf16x8 R0 = pack_frag(b1[0], b1[1]);   // r1 -> A3 s=0 slots
                bf16x8 R1 = pack_frag(b2[0], b2[1]);   // r2 -> A3 s=1 slots
                unsigned short* dst = &lds[4096 + ((k2 & 1) << 10) + (lane << 3)];
                *(bf16x8*)dst         = R0;
                *(bf16x8*)(dst + 512) = R1;
            }
        } else {
            int k3 = k - 2;
            if (k3 >= 0) {
                float xdc = xd_n;
                if (k3 + 1 < CHUNKS)
                    xd_n = x[((rowbase + ((k3 + 1) << 4) + c0) << 6) + i];
                const unsigned short* s = &lds[4096 + ((k3 & 1) << 10) + (lane << 3)];
                bf16x8 RB0 = *(const bf16x8*)s, RB1 = *(const bf16x8*)(s + 512);
                float p = 0.f;
                #pragma unroll
                for (int t = 0; t < 4; ++t) {
                    f32x4 acc;
                    acc[0] = fmaf(xdc, bf_lo(wxp[t].x), b3av[t][0]);
                    acc[1] = fmaf(xdc, bf_hi(wxp[t].x), b3av[t][1]);
                    acc[2] = fmaf(xdc, bf_lo(wxp[t].y), b3av[t][2]);
                    acc[3] = fmaf(xdc, bf_hi(wxp[t].y), b3av[t][3]);
                    acc = mfma16(W[2 * t], RB0, acc);
                    acc = mfma16(W[2 * t + 1], RB1, acc);
                    #pragma unroll
                    for (int r = 0; r < 4; ++r)
                        p = fmaf(fmaxf(acc[r], 0.f), w3bv[t][r], p);
                }
                p += __shfl_xor(p, 16);
                p += __shfl_xor(p, 32);
                if (lane < 16)
                    out[((rowbase + (k3 << 4) + c0) << 6) + i] = fmaxf(p + bb, 0.f);
            }
        }
        __syncthreads();
    }
}

extern "C" void kernel_launch(void* const* d_in, const int* in_sizes, int n_in,
                              void* d_out, int out_size, void* d_ws, size_t ws_size,
                              hipStream_t stream) {
    (void)in_sizes; (void)n_in; (void)out_size; (void)d_ws; (void)ws_size;
    const float* x   = (const float*)d_in[0];
    const float* W1a = (const float*)d_in[1];
    const float* W1b = (const float*)d_in[2];
    const float* W2a = (const float*)d_in[3];
    const float* W2b = (const float*)d_in[4];
    const float* W3a = (const float*)d_in[5];
    const float* b3a = (const float*)d_in[6];
    const float* W3b = (const float*)d_in[7];
    const float* b3b = (const float*)d_in[8];
    float* out = (float*)d_out;

    main_kernel<<<1024, 256, 0, stream>>>(x, W1a, W1b, W2a, W2b, W3a, b3a, W3b, b3b, out);
}

// Round 7
// 138.002 us; speedup vs baseline: 1.2431x; 1.2431x over previous
//
#include <hip/hip_runtime.h>

// N=64 nodes, H=64, M=32, B=16384.
// Grid: 512 blocks = 64 i x 8 bg; 4 waves/block; NO __shared__, NO barriers.
// Monolithic per-wave network (R3 structure, best so far) + 2-way chunk ILP:
// each wave runs TWO independent 16-row streams per loop iteration so the SIMD
// has 4 independent dependency chains (2 streams x 2 waves) to hide MFMA/VALU
// latency (R3-R6 evidence: 2 waves/SIMD is register-structural; the ~55% stall
// was chain latency, so add ILP, not occupancy. R6 barrier pipeline regressed).
// Epilogue dot is now an MFMA with w3b as a broadcast K-permuted A-fragment
// (no cross-lane shuffles). K-columns of W1b/W2b/W3a/W3b permuted by sigma so
// each phase's MFMA D regs, after relu+pack, ARE the next B-operand fragments.

typedef short bf16x8 __attribute__((ext_vector_type(8)));
typedef float f32x4  __attribute__((ext_vector_type(4)));
typedef unsigned int u32x4 __attribute__((ext_vector_type(4)));

__device__ __forceinline__ unsigned int pack2(float a, float b) {
    // f32->bf16 pair pack (a -> low16): 2 adds + 1 v_perm
    union { float f; unsigned int u; } ua, ub; ua.f = a; ub.f = b;
    return __builtin_amdgcn_perm(ub.u + 0x8000u, ua.u + 0x8000u, 0x07060302u);
}

__device__ __forceinline__ float bf_lo(unsigned int u) {
    union { unsigned int u; float f; } v; v.u = u << 16; return v.f;
}
__device__ __forceinline__ float bf_hi(unsigned int u) {
    union { unsigned int u; float f; } v; v.u = u & 0xFFFF0000u; return v.f;
}

__device__ __forceinline__ f32x4 mfma16(bf16x8 a, bf16x8 b, f32x4 c) {
    return __builtin_amdgcn_mfma_f32_16x16x32_bf16(a, b, c, 0, 0, 0);
}

// pack two relu'd f32x4 D-blocks into one bf16x8 B-operand fragment
__device__ __forceinline__ bf16x8 pack_frag(f32x4 lo, f32x4 hi) {
    union { u32x4 u; bf16x8 v; } r;
    r.u[0] = pack2(fmaxf(lo[0], 0.f), fmaxf(lo[1], 0.f));
    r.u[1] = pack2(fmaxf(lo[2], 0.f), fmaxf(lo[3], 0.f));
    r.u[2] = pack2(fmaxf(hi[0], 0.f), fmaxf(hi[1], 0.f));
    r.u[3] = pack2(fmaxf(hi[2], 0.f), fmaxf(hi[3], 0.f));
    return r.v;
}

__device__ __forceinline__ bf16x8 cvt_frag2(const float* __restrict__ plo,
                                            const float* __restrict__ phi) {
    f32x4 f0 = *(const f32x4*)plo;
    f32x4 f1 = *(const f32x4*)phi;
    union { u32x4 u; bf16x8 v; } r;
    r.u[0] = pack2(f0[0], f0[1]);
    r.u[1] = pack2(f0[2], f0[3]);
    r.u[2] = pack2(f1[0], f1[1]);
    r.u[3] = pack2(f1[2], f1[3]);
    return r.v;
}

__device__ __forceinline__ bf16x8 cvt_frag2_m(const float* __restrict__ plo,
                                              const float* __restrict__ phi,
                                              const unsigned int* M) {
    f32x4 f0 = *(const f32x4*)plo;
    f32x4 f1 = *(const f32x4*)phi;
    union { u32x4 u; bf16x8 v; } r;
    r.u[0] = pack2(f0[0], f0[1]) & M[0];
    r.u[1] = pack2(f0[2], f0[3]) & M[1];
    r.u[2] = pack2(f1[0], f1[1]) & M[2];
    r.u[3] = pack2(f1[2], f1[3]) & M[3];
    return r.v;
}

__global__ __launch_bounds__(256) void prep_x(const float* __restrict__ x,
                                              unsigned short* __restrict__ xb) {
    int j = (blockIdx.x * 256 + threadIdx.x) * 8;
    f32x4 a = *(const f32x4*)&x[j];
    f32x4 b = *(const f32x4*)&x[j + 4];
    u32x4 r = { pack2(a[0], a[1]), pack2(a[2], a[3]), pack2(b[0], b[1]), pack2(b[2], b[3]) };
    *(u32x4*)&xb[j] = r;
}

__global__ __launch_bounds__(256, 2) void main_kernel(
    const float* __restrict__ x,
    const float* __restrict__ W1a, const float* __restrict__ W1b,
    const float* __restrict__ W2a, const float* __restrict__ W2b,
    const float* __restrict__ W3a, const float* __restrict__ b3a,
    const float* __restrict__ W3b, const float* __restrict__ b3b,
    const unsigned short* __restrict__ xb,
    float* __restrict__ out)
{
    const int i    = blockIdx.x & 63;   // same-i blocks -> same XCD (stride 64 % 8 == 0)
    const int bg   = blockIdx.x >> 6;   // 0..7
    const int tid  = threadIdx.x;
    const int w    = tid >> 6;
    const int lane = tid & 63;
    const int q    = lane >> 4;
    const int c0   = lane & 15;

    // masks zeroing weight input-column i of W1a/W2a (== masking x column i)
    unsigned int M[2][4];
    {
        const unsigned int halfmask = (i & 1) ? 0x0000FFFFu : 0xFFFF0000u;
        const int dz = (i >> 1) & 3;
        #pragma unroll
        for (int s = 0; s < 2; ++s) {
            bool hit = ((i >> 3) == s * 4 + q);
            #pragma unroll
            for (int d = 0; d < 4; ++d)
                M[s][d] = (hit && d == dz) ? halfmask : 0xFFFFFFFFu;
        }
    }

    // ---- weights for node i -> registers (bf16 A-fragments), K-permuted where needed ----
    // Phase A (W1a/W2a): natural K order. frag elem j = W[i][t*16+c0][s*32+q*8+j]
    bf16x8 A1[4][2], A2[4][2];
    {
        const float* p1 = W1a + (i << 12);
        const float* p2 = W2a + (i << 12);
        #pragma unroll
        for (int t = 0; t < 4; ++t)
            #pragma unroll
            for (int s = 0; s < 2; ++s) {
                int off = (((t << 4) + c0) << 6) + (s << 5) + (q << 3);
                A1[t][s] = cvt_frag2_m(p1 + off, p1 + off + 4, M[s]);
                A2[t][s] = cvt_frag2_m(p2 + off, p2 + off + 4, M[s]);
            }
    }
    // Phase B (W1b/W2b): K permuted by sigma(s,q,j) = 32s + 16(j>>2) + 4q + (j&3)
    bf16x8 F1[2][2], F2[2][2];
    {
        const float* p1 = W1b + (i << 11);
        const float* p2 = W2b + (i << 11);
        #pragma unroll
        for (int t = 0; t < 2; ++t)
            #pragma unroll
            for (int s = 0; s < 2; ++s) {
                int base = (((t << 4) + c0) << 6) + (s << 5) + (q << 2);
                F1[t][s] = cvt_frag2(p1 + base, p1 + base + 16);
                F2[t][s] = cvt_frag2(p2 + base, p2 + base + 16);
            }
    }
    // Phase C (W3a, first 64 concat cols): col = 32s + 16(j>>2) + 4q + (j&3)
    bf16x8 A3[4][2];
    {
        const float* p3 = W3a + (i << 13);
        #pragma unroll
        for (int t = 0; t < 4; ++t)
            #pragma unroll
            for (int s = 0; s < 2; ++s) {
                int base = (((t << 4) + c0) << 7) + (s << 5) + (q << 2);
                A3[t][s] = cvt_frag2(p3 + base, p3 + base + 16);
            }
    }
    // Dot-layer (W3b): broadcast A-fragment, K permuted by the same sigma, all lanes equal.
    bf16x8 WB[2];
    {
        const float* pb = W3b + (i << 6);
        #pragma unroll
        for (int s = 0; s < 2; ++s) {
            int base = (s << 5) + (q << 2);
            WB[s] = cvt_frag2(pb + base, pb + base + 16);
        }
    }
    // C-init constants: b3a (f32) + rank-1 column of W3a (bf16-packed)
    f32x4 b3av[4];
    uint2  wxp[4];
    #pragma unroll
    for (int t = 0; t < 4; ++t) {
        int h0 = (i << 6) + (t << 4) + (q << 2);
        b3av[t] = *(const f32x4*)&b3a[h0];
        float v0 = W3a[(i << 13) + (((t << 4) + (q << 2) + 0) << 7) + 64 + i];
        float v1 = W3a[(i << 13) + (((t << 4) + (q << 2) + 1) << 7) + 64 + i];
        float v2 = W3a[(i << 13) + (((t << 4) + (q << 2) + 2) << 7) + 64 + i];
        float v3 = W3a[(i << 13) + (((t << 4) + (q << 2) + 3) << 7) + 64 + i];
        wxp[t].x = pack2(v0, v1);
        wxp[t].y = pack2(v2, v3);
    }
    const float bb = b3b[i];

    // one full network chunk (16 rows) for `row`; returns via global store
    auto process = [&](int row) {
        const unsigned short* xp = xb + (row << 6);
        bf16x8 X0 = *(const bf16x8*)&xp[(q << 3)];
        bf16x8 X1 = *(const bf16x8*)&xp[32 + (q << 3)];
        float  xd = x[(row << 6) + i];

        // phase A: x -> Ha (W1a), x -> Hb (W2a)
        f32x4 a1[4], a2[4];
        #pragma unroll
        for (int t = 0; t < 4; ++t) {
            f32x4 z = {0.f, 0.f, 0.f, 0.f};
            f32x4 u = mfma16(A1[t][0], X0, z);
            a1[t]   = mfma16(A1[t][1], X1, u);
            f32x4 v = mfma16(A2[t][0], X0, z);
            a2[t]   = mfma16(A2[t][1], X1, v);
        }
        bf16x8 HB0 = pack_frag(a1[0], a1[1]);
        bf16x8 HB1 = pack_frag(a1[2], a1[3]);
        bf16x8 GB0 = pack_frag(a2[0], a2[1]);
        bf16x8 GB1 = pack_frag(a2[2], a2[3]);

        // phase B: Ha -> r1 (W1b), Hb -> r2 (W2b)
        f32x4 b1[2], b2[2];
        #pragma unroll
        for (int t = 0; t < 2; ++t) {
            f32x4 z = {0.f, 0.f, 0.f, 0.f};
            f32x4 u = mfma16(F1[t][0], HB0, z);
            b1[t]   = mfma16(F1[t][1], HB1, u);
            f32x4 v = mfma16(F2[t][0], GB0, z);
            b2[t]   = mfma16(F2[t][1], GB1, v);
        }
        bf16x8 RB0 = pack_frag(b1[0], b1[1]);   // r1 -> A3 s=0 slots
        bf16x8 RB1 = pack_frag(b2[0], b2[1]);   // r2 -> A3 s=1 slots

        // phase C: h = W3a'*[r1;r2] + xd*w3x + b3a (pre-relu, f32)
        f32x4 acc[4];
        #pragma unroll
        for (int t = 0; t < 4; ++t) {
            f32x4 c;
            c[0] = fmaf(xd, bf_lo(wxp[t].x), b3av[t][0]);
            c[1] = fmaf(xd, bf_hi(wxp[t].x), b3av[t][1]);
            c[2] = fmaf(xd, bf_lo(wxp[t].y), b3av[t][2]);
            c[3] = fmaf(xd, bf_hi(wxp[t].y), b3av[t][3]);
            c = mfma16(A3[t][0], RB0, c);
            acc[t] = mfma16(A3[t][1], RB1, c);
        }
        // dot via MFMA: relu(h) packs into B-layout by the same sigma; WB broadcast rows
        bf16x8 HD0 = pack_frag(acc[0], acc[1]);
        bf16x8 HD1 = pack_frag(acc[2], acc[3]);
        f32x4 pz = {0.f, 0.f, 0.f, 0.f};
        pz = mfma16(WB[0], HD0, pz);
        pz = mfma16(WB[1], HD1, pz);
        if (lane < 16) out[(row << 6) + i] = fmaxf(pz[0] + bb, 0.f);
    };

    // this wave's 512 rows as two independent 256-row streams (2-way chunk ILP)
    const int r0 = (((bg << 2) + w) << 9) + c0;
    for (int k = 0; k < 16; ++k) {
        int rA = r0 + (k << 4);
        process(rA);          // stream A
        process(rA + 256);    // stream B (independent DAG; compiler interleaves)
    }
}

extern "C" void kernel_launch(void* const* d_in, const int* in_sizes, int n_in,
                              void* d_out, int out_size, void* d_ws, size_t ws_size,
                              hipStream_t stream) {
    (void)in_sizes; (void)n_in; (void)out_size; (void)ws_size;
    const float* x   = (const float*)d_in[0];
    const float* W1a = (const float*)d_in[1];
    const float* W1b = (const float*)d_in[2];
    const float* W2a = (const float*)d_in[3];
    const float* W2b = (const float*)d_in[4];
    const float* W3a = (const float*)d_in[5];
    const float* b3a = (const float*)d_in[6];
    const float* W3b = (const float*)d_in[7];
    const float* b3b = (const float*)d_in[8];
    float* out = (float*)d_out;
    unsigned short* xb = (unsigned short*)d_ws;

    prep_x<<<512, 256, 0, stream>>>(x, xb);
    main_kernel<<<512, 256, 0, stream>>>(x, W1a, W1b, W2a, W2b, W3a, b3a, W3b, b3b, xb, out);
}

// Round 8
// 132.350 us; speedup vs baseline: 1.2962x; 1.0427x over previous
//
#include <hip/hip_runtime.h>

// N=64 nodes, H=64, M=32, B=16384.
// Grid: 512 blocks = 64 i x 8 bg; 4 waves/block; NO __shared__, NO barriers.
// Monolithic per-wave network + FUSED 2-stream ILP: both 16-row streams are
// computed in one loop body with stream-index-inner loops, so independent
// instructions alternate by construction (R7 lesson: separate process() calls
// got serialized by the compiler -> zero ILP gain). x fragments + xd are
// prefetched one chunk ahead for both streams (R3 had this; R7 dropped it).
// Weights stay register/AGPR-resident (MFMA reads AGPR operands natively on
// gfx950 -- R7 counters show no copy tax once the gfx94x 4cyc-formula inflation
// of VALUBusy is corrected). Epilogue dot via MFMA with broadcast w3b fragment.
// K-columns of W1b/W2b/W3a/W3b permuted by sigma(s,q,j)=32s+16(j>>2)+4q+(j&3)
// so each phase's MFMA D regs, after relu+pack, ARE the next B-operand frags.

typedef short bf16x8 __attribute__((ext_vector_type(8)));
typedef float f32x4  __attribute__((ext_vector_type(4)));
typedef unsigned int u32x4 __attribute__((ext_vector_type(4)));

__device__ __forceinline__ unsigned int pack2(float a, float b) {
    // f32->bf16 pair pack (a -> low16): 2 adds + 1 v_perm
    union { float f; unsigned int u; } ua, ub; ua.f = a; ub.f = b;
    return __builtin_amdgcn_perm(ub.u + 0x8000u, ua.u + 0x8000u, 0x07060302u);
}

__device__ __forceinline__ float bf_lo(unsigned int u) {
    union { unsigned int u; float f; } v; v.u = u << 16; return v.f;
}
__device__ __forceinline__ float bf_hi(unsigned int u) {
    union { unsigned int u; float f; } v; v.u = u & 0xFFFF0000u; return v.f;
}

__device__ __forceinline__ f32x4 mfma16(bf16x8 a, bf16x8 b, f32x4 c) {
    return __builtin_amdgcn_mfma_f32_16x16x32_bf16(a, b, c, 0, 0, 0);
}

__device__ __forceinline__ bf16x8 pack_frag(f32x4 lo, f32x4 hi) {
    union { u32x4 u; bf16x8 v; } r;
    r.u[0] = pack2(fmaxf(lo[0], 0.f), fmaxf(lo[1], 0.f));
    r.u[1] = pack2(fmaxf(lo[2], 0.f), fmaxf(lo[3], 0.f));
    r.u[2] = pack2(fmaxf(hi[0], 0.f), fmaxf(hi[1], 0.f));
    r.u[3] = pack2(fmaxf(hi[2], 0.f), fmaxf(hi[3], 0.f));
    return r.v;
}

__device__ __forceinline__ bf16x8 cvt_frag2(const float* __restrict__ plo,
                                            const float* __restrict__ phi) {
    f32x4 f0 = *(const f32x4*)plo;
    f32x4 f1 = *(const f32x4*)phi;
    union { u32x4 u; bf16x8 v; } r;
    r.u[0] = pack2(f0[0], f0[1]);
    r.u[1] = pack2(f0[2], f0[3]);
    r.u[2] = pack2(f1[0], f1[1]);
    r.u[3] = pack2(f1[2], f1[3]);
    return r.v;
}

__device__ __forceinline__ bf16x8 cvt_frag2_m(const float* __restrict__ plo,
                                              const float* __restrict__ phi,
                                              const unsigned int* M) {
    f32x4 f0 = *(const f32x4*)plo;
    f32x4 f1 = *(const f32x4*)phi;
    union { u32x4 u; bf16x8 v; } r;
    r.u[0] = pack2(f0[0], f0[1]) & M[0];
    r.u[1] = pack2(f0[2], f0[3]) & M[1];
    r.u[2] = pack2(f1[0], f1[1]) & M[2];
    r.u[3] = pack2(f1[2], f1[3]) & M[3];
    return r.v;
}

__global__ __launch_bounds__(256) void prep_x(const float* __restrict__ x,
                                              unsigned short* __restrict__ xb) {
    int j = (blockIdx.x * 256 + threadIdx.x) * 8;
    f32x4 a = *(const f32x4*)&x[j];
    f32x4 b = *(const f32x4*)&x[j + 4];
    u32x4 r = { pack2(a[0], a[1]), pack2(a[2], a[3]), pack2(b[0], b[1]), pack2(b[2], b[3]) };
    *(u32x4*)&xb[j] = r;
}

__global__ __launch_bounds__(256, 2) void main_kernel(
    const float* __restrict__ x,
    const float* __restrict__ W1a, const float* __restrict__ W1b,
    const float* __restrict__ W2a, const float* __restrict__ W2b,
    const float* __restrict__ W3a, const float* __restrict__ b3a,
    const float* __restrict__ W3b, const float* __restrict__ b3b,
    const unsigned short* __restrict__ xb,
    float* __restrict__ out)
{
    const int i    = blockIdx.x & 63;   // same-i blocks -> same XCD (stride 64 % 8 == 0)
    const int bg   = blockIdx.x >> 6;   // 0..7
    const int tid  = threadIdx.x;
    const int w    = tid >> 6;
    const int lane = tid & 63;
    const int q    = lane >> 4;
    const int c0   = lane & 15;

    // masks zeroing weight input-column i of W1a/W2a (== masking x column i)
    unsigned int M[2][4];
    {
        const unsigned int halfmask = (i & 1) ? 0x0000FFFFu : 0xFFFF0000u;
        const int dz = (i >> 1) & 3;
        #pragma unroll
        for (int s = 0; s < 2; ++s) {
            bool hit = ((i >> 3) == s * 4 + q);
            #pragma unroll
            for (int d = 0; d < 4; ++d)
                M[s][d] = (hit && d == dz) ? halfmask : 0xFFFFFFFFu;
        }
    }

    // ---- weights for node i -> registers (bf16 A-fragments), K-permuted where needed ----
    bf16x8 A1[4][2], A2[4][2];
    {
        const float* p1 = W1a + (i << 12);
        const float* p2 = W2a + (i << 12);
        #pragma unroll
        for (int t = 0; t < 4; ++t)
            #pragma unroll
            for (int s = 0; s < 2; ++s) {
                int off = (((t << 4) + c0) << 6) + (s << 5) + (q << 3);
                A1[t][s] = cvt_frag2_m(p1 + off, p1 + off + 4, M[s]);
                A2[t][s] = cvt_frag2_m(p2 + off, p2 + off + 4, M[s]);
            }
    }
    bf16x8 F1[2][2], F2[2][2];
    {
        const float* p1 = W1b + (i << 11);
        const float* p2 = W2b + (i << 11);
        #pragma unroll
        for (int t = 0; t < 2; ++t)
            #pragma unroll
            for (int s = 0; s < 2; ++s) {
                int base = (((t << 4) + c0) << 6) + (s << 5) + (q << 2);
                F1[t][s] = cvt_frag2(p1 + base, p1 + base + 16);
                F2[t][s] = cvt_frag2(p2 + base, p2 + base + 16);
            }
    }
    bf16x8 A3[4][2];
    {
        const float* p3 = W3a + (i << 13);
        #pragma unroll
        for (int t = 0; t < 4; ++t)
            #pragma unroll
            for (int s = 0; s < 2; ++s) {
                int base = (((t << 4) + c0) << 7) + (s << 5) + (q << 2);
                A3[t][s] = cvt_frag2(p3 + base, p3 + base + 16);
            }
    }
    bf16x8 WB[2];
    {
        const float* pb = W3b + (i << 6);
        #pragma unroll
        for (int s = 0; s < 2; ++s) {
            int base = (s << 5) + (q << 2);
            WB[s] = cvt_frag2(pb + base, pb + base + 16);
        }
    }
    f32x4 b3av[4];
    uint2  wxp[4];
    #pragma unroll
    for (int t = 0; t < 4; ++t) {
        int h0 = (i << 6) + (t << 4) + (q << 2);
        b3av[t] = *(const f32x4*)&b3a[h0];
        float v0 = W3a[(i << 13) + (((t << 4) + (q << 2) + 0) << 7) + 64 + i];
        float v1 = W3a[(i << 13) + (((t << 4) + (q << 2) + 1) << 7) + 64 + i];
        float v2 = W3a[(i << 13) + (((t << 4) + (q << 2) + 2) << 7) + 64 + i];
        float v3 = W3a[(i << 13) + (((t << 4) + (q << 2) + 3) << 7) + 64 + i];
        wxp[t].x = pack2(v0, v1);
        wxp[t].y = pack2(v2, v3);
    }
    const float bb = b3b[i];

    // this wave's 512 rows as two fused 256-row streams
    const int r0 = (((bg << 2) + w) << 9) + c0;

    bf16x8 X0[2], X1[2];
    float  xd[2];
    #pragma unroll
    for (int s2 = 0; s2 < 2; ++s2) {
        int row = r0 + (s2 << 8);
        const unsigned short* xp = xb + (row << 6);
        X0[s2] = *(const bf16x8*)&xp[(q << 3)];
        X1[s2] = *(const bf16x8*)&xp[32 + (q << 3)];
        xd[s2] = x[(row << 6) + i];
    }

    for (int k = 0; k < 16; ++k) {
        // prefetch next chunk, both streams
        bf16x8 nX0[2], nX1[2];
        float  nxd[2];
        {
            int kn = (k < 15) ? k + 1 : 15;
            #pragma unroll
            for (int s2 = 0; s2 < 2; ++s2) {
                int row = r0 + (kn << 4) + (s2 << 8);
                const unsigned short* xp = xb + (row << 6);
                nX0[s2] = *(const bf16x8*)&xp[(q << 3)];
                nX1[s2] = *(const bf16x8*)&xp[32 + (q << 3)];
                nxd[s2] = x[(row << 6) + i];
            }
        }

        // ---- phase A: x -> Ha (W1a), x -> Hb (W2a), both streams interleaved ----
        f32x4 a1[2][4], a2[2][4];
        #pragma unroll
        for (int t = 0; t < 4; ++t)
            #pragma unroll
            for (int s2 = 0; s2 < 2; ++s2) {
                f32x4 z = {0.f, 0.f, 0.f, 0.f};
                f32x4 u = mfma16(A1[t][0], X0[s2], z);
                a1[s2][t] = mfma16(A1[t][1], X1[s2], u);
                f32x4 v = mfma16(A2[t][0], X0[s2], z);
                a2[s2][t] = mfma16(A2[t][1], X1[s2], v);
            }
        bf16x8 HB0[2], HB1[2], GB0[2], GB1[2];
        #pragma unroll
        for (int s2 = 0; s2 < 2; ++s2) {
            HB0[s2] = pack_frag(a1[s2][0], a1[s2][1]);
            HB1[s2] = pack_frag(a1[s2][2], a1[s2][3]);
            GB0[s2] = pack_frag(a2[s2][0], a2[s2][1]);
            GB1[s2] = pack_frag(a2[s2][2], a2[s2][3]);
        }

        // ---- phase B: Ha -> r1 (W1b), Hb -> r2 (W2b) ----
        f32x4 b1[2][2], b2[2][2];
        #pragma unroll
        for (int t = 0; t < 2; ++t)
            #pragma unroll
            for (int s2 = 0; s2 < 2; ++s2) {
                f32x4 z = {0.f, 0.f, 0.f, 0.f};
                f32x4 u = mfma16(F1[t][0], HB0[s2], z);
                b1[s2][t] = mfma16(F1[t][1], HB1[s2], u);
                f32x4 v = mfma16(F2[t][0], GB0[s2], z);
                b2[s2][t] = mfma16(F2[t][1], GB1[s2], v);
            }
        bf16x8 RB0[2], RB1[2];
        #pragma unroll
        for (int s2 = 0; s2 < 2; ++s2) {
            RB0[s2] = pack_frag(b1[s2][0], b1[s2][1]);   // r1 -> A3 s=0 slots
            RB1[s2] = pack_frag(b2[s2][0], b2[s2][1]);   // r2 -> A3 s=1 slots
        }

        // ---- phase C: h = W3a'*[r1;r2] + xd*w3x + b3a (pre-relu, f32) ----
        f32x4 acc[2][4];
        #pragma unroll
        for (int t = 0; t < 4; ++t)
            #pragma unroll
            for (int s2 = 0; s2 < 2; ++s2) {
                f32x4 c;
                c[0] = fmaf(xd[s2], bf_lo(wxp[t].x), b3av[t][0]);
                c[1] = fmaf(xd[s2], bf_hi(wxp[t].x), b3av[t][1]);
                c[2] = fmaf(xd[s2], bf_lo(wxp[t].y), b3av[t][2]);
                c[3] = fmaf(xd[s2], bf_hi(wxp[t].y), b3av[t][3]);
                c = mfma16(A3[t][0], RB0[s2], c);
                acc[s2][t] = mfma16(A3[t][1], RB1[s2], c);
            }

        // ---- epilogue dot via MFMA (broadcast w3b), both streams ----
        #pragma unroll
        for (int s2 = 0; s2 < 2; ++s2) {
            bf16x8 HD0 = pack_frag(acc[s2][0], acc[s2][1]);
            bf16x8 HD1 = pack_frag(acc[s2][2], acc[s2][3]);
            f32x4 pz = {0.f, 0.f, 0.f, 0.f};
            pz = mfma16(WB[0], HD0, pz);
            pz = mfma16(WB[1], HD1, pz);
            if (lane < 16) {
                int row = r0 + (k << 4) + (s2 << 8);
                out[(row << 6) + i] = fmaxf(pz[0] + bb, 0.f);
            }
        }

        #pragma unroll
        for (int s2 = 0; s2 < 2; ++s2) {
            X0[s2] = nX0[s2]; X1[s2] = nX1[s2]; xd[s2] = nxd[s2];
        }
    }
}

extern "C" void kernel_launch(void* const* d_in, const int* in_sizes, int n_in,
                              void* d_out, int out_size, void* d_ws, size_t ws_size,
                              hipStream_t stream) {
    (void)in_sizes; (void)n_in; (void)out_size; (void)ws_size;
    const float* x   = (const float*)d_in[0];
    const float* W1a = (const float*)d_in[1];
    const float* W1b = (const float*)d_in[2];
    const float* W2a = (const float*)d_in[3];
    const float* W2b = (const float*)d_in[4];
    const float* W3a = (const float*)d_in[5];
    const float* b3a = (const float*)d_in[6];
    const float* W3b = (const float*)d_in[7];
    const float* b3b = (const float*)d_in[8];
    float* out = (float*)d_out;
    unsigned short* xb = (unsigned short*)d_ws;

    prep_x<<<512, 256, 0, stream>>>(x, xb);
    main_kernel<<<512, 256, 0, stream>>>(x, W1a, W1b, W2a, W2b, W3a, b3a, W3b, b3b, xb, out);
}